// Round 6
// baseline (158.504 us; speedup 1.0000x reference)
//
#include <hip/hip_runtime.h>
#include <cstdint>

typedef __attribute__((ext_vector_type(8))) __bf16 bf16x8;
typedef __attribute__((ext_vector_type(4))) float f32x4;
typedef __attribute__((ext_vector_type(4))) uint32_t u32x4;

// ---- problem constants ----
#define NB   16
#define CIN  256
#define COUT 256
#define HP   66          // padded H
#define WP   66          // padded W
#define KTOT 2304        // 9*256
#define XPB  (HP*WP*256)            // elems per batch image = 1,115,136
#define XPAD_ELEMS (NB*XPB)

__device__ __forceinline__ uint16_t f2bf(float f) {
  uint32_t u = __builtin_bit_cast(uint32_t, f);
  u = (u + 0x7FFFu + ((u >> 16) & 1u)) >> 16;   // round-to-nearest-even
  return (uint16_t)u;
}

// ---------------- fused prep: xpose (2048 blk) | border (1040 blk) | wprep (288 blk)
__global__ void prep_kernel(const float* __restrict__ x, const float* __restrict__ w,
                            uint16_t* __restrict__ xpad, uint16_t* __restrict__ bw) {
  const int bid = blockIdx.x;
  const int tid = threadIdx.x;
  if (bid < 2048) {
    // transpose+cast: x NCHW fp32 -> xpad[b][h+1][w+1][c] bf16 (interior only)
    const int lane = tid & 63;
    const int wvi = tid >> 6;                 // 0..3
    const int chalf = bid & 1;
    const int h = (bid >> 1) & 63;
    const int b = bid >> 7;
    const int c0 = chalf * 128 + wvi * 32;
    const float* src = x + ((size_t)(b * 256 + c0) * 64 + h) * 64 + lane;
    uint16_t* dst = xpad + ((size_t)(b * HP + h + 1) * WP + lane + 1) * 256 + c0;
    #pragma unroll
    for (int g = 0; g < 4; ++g) {             // 8 channels per 16B store
      u32x4 d;
      #pragma unroll
      for (int k = 0; k < 4; ++k) {
        const float v0 = src[(size_t)(g * 8 + 2 * k + 0) * 4096];
        const float v1 = src[(size_t)(g * 8 + 2 * k + 1) * 4096];
        d[k] = (uint32_t)f2bf(v0) | ((uint32_t)f2bf(v1) << 16);
      }
      *(u32x4*)(dst + g * 8) = d;
    }
  } else if (bid < 3088) {
    // zero the pad border (u64 stores)
    const int idx = (bid - 2048) * 256 + tid;   // 0 .. 266239 exact
    const int b = idx / 16640;
    const int r = idx - b * 16640;
    uint64_t* base = (uint64_t*)(xpad + (size_t)b * XPB);
    int off;
    if (r < 4224) {                    // h=0 full row
      off = r;
    } else if (r < 8448) {             // h=65 full row
      off = 274560 + (r - 4224);
    } else if (r < 12544) {            // w=0 column, h=1..64
      const int i = r - 8448;
      off = (1 + (i >> 6)) * 4224 + (i & 63);
    } else {                           // w=65 column, h=1..64
      const int i = r - 12544;
      off = (1 + (i >> 6)) * 4224 + 4160 + (i & 63);
    }
    base[off] = 0;
  } else {
    // weight reorder: w[co][ci][3][3] fp32 -> bw[co][tap][ci] bf16
    const int gid = (bid - 3088) * 256 + tid;   // 0 .. 73727
    const int co = gid / 288;                   // 288 = 9 taps * 32 ci-groups
    const int r = gid - co * 288;
    const int tap = r >> 5;
    const int ci0 = (r & 31) * 8;
    u32x4 d;
    #pragma unroll
    for (int k = 0; k < 4; ++k) {
      const float v0 = w[((co * 256 + ci0 + 2 * k + 0) * 9) + tap];
      const float v1 = w[((co * 256 + ci0 + 2 * k + 1) * 9) + tap];
      d[k] = (uint32_t)f2bf(v0) | ((uint32_t)f2bf(v1) << 16);
    }
    *(u32x4*)(bw + co * KTOT + tap * 256 + ci0) = d;
  }
}

// ---------------- async 16B global -> LDS --------------------------------------------
__device__ __forceinline__ void gl_lds16(const void* g, void* l) {
  __builtin_amdgcn_global_load_lds(
      (__attribute__((address_space(1))) void*)(uintptr_t)g,
      (__attribute__((address_space(3))) void*)(uint32_t)(uintptr_t)l,
      16, 0, 0);
}

// ---------------- implicit GEMM: BM=128, BN=64, BK=64; 256 threads (4 waves) --------
// wave grid 4x1 (wave tile 32x64). A: direct global->VGPR (reg dbuf, no LDS).
// B: global_load_lds staged, double-buffered LDS (16 KB). 512 blocks = 2/CU.
// K order: ci-chunk OUTER, tap INNER -> A slab (72 KB/m-tile) stays L2-resident
// across the 9 taps; barrier drains see ~200cy L2 hits instead of ~900cy HBM misses.
__global__ __launch_bounds__(256, 2) void gemm_kernel(
    const uint16_t* __restrict__ xpad, const uint16_t* __restrict__ bw,
    const float* __restrict__ bias, float* __restrict__ out) {
  __shared__ uint16_t lB[2][64 * 64];    // 8 KB per buffer
  const int tid = threadIdx.x;
  const int wv = tid >> 6, lane = tid & 63;
  const int quad = lane >> 4, l15 = lane & 15, l7 = lane & 7;

  // XCD swizzle: 4 n-tiles of one m-tile co-resident on one XCD -> A L2-reuse
  const int xcd = blockIdx.x & 7;
  const int grp = blockIdx.x >> 3;        // 0..63 per XCD
  const int mtile = (xcd << 4) + (grp >> 2);
  const int ntile = grp & 3;
  const int n0 = ntile * 64;
  const int m0 = mtile * 128;
  const int bidx = m0 >> 10;              // batch image
  const int q0 = m0 & 1023;               // permuted pixel offset (multiple of 128)

  // per-lane A pixel bases: rows m = wv*32 + r*16 + l15, r in {0,1}
  int P[2];
  #pragma unroll
  for (int r = 0; r < 2; ++r) {
    const int m = wv * 32 + r * 16 + l15;
    const int p = q0 + m;
    const int oh = 2 * ((p >> 4) & 15) + ((p >> 9) & 1);
    const int ow = 2 * (p & 15) + ((p >> 8) & 1);
    P[r] = ((bidx * HP + 2 * oh) * WP + 2 * ow) * 256;
  }

  // B staging: 2 chunk-slots/thread (512 chunks of 16B); XOR chunk swizzle
  int b_goff[2];
  #pragma unroll
  for (int t = 0; t < 2; ++t) {
    const int slot = t * 256 + tid;
    const int n = slot >> 3;
    const int kc = (slot & 7) ^ (n & 7);
    b_goff[t] = (n0 + n) * KTOT + kc * 8;
  }

  // LDS B frag byte-offsets (swizzle-matched; 0 conflicts measured r1-r5)
  int boff[4][2];
  #pragma unroll
  for (int c = 0; c < 4; ++c)
    #pragma unroll
    for (int s = 0; s < 2; ++s)
      boff[c][s] = (c * 16 + l15) * 128 + (((s * 4 + quad) ^ l7) * 16);

  f32x4 acc[2][4];
  #pragma unroll
  for (int r = 0; r < 2; ++r)
    #pragma unroll
    for (int c = 0; c < 4; ++c)
      acc[r][c] = (f32x4){0.f, 0.f, 0.f, 0.f};

  bf16x8 Ar[2][2][2];   // [buf][r][s] register-double-buffered A frags

  // K-step decode: it in [0,36); cc = it/9 (ci chunk, OUTER), tap = it%9 (INNER)
  auto stageB = [&](int it, int buf) {
    const int cc = (it * 57) >> 9;        // it/9 for it<36
    const int tap = it - cc * 9;
    const uint16_t* bptr = bw + tap * 256 + cc * 64;
    char* lb = (char*)&lB[buf][0];
    #pragma unroll
    for (int t = 0; t < 2; ++t)
      gl_lds16(bptr + b_goff[t], lb + (t * 256 + wv * 64) * 16);
  };
  auto loadA = [&](int it, bf16x8 (&dst)[2][2]) {
    const int cc = (it * 57) >> 9;
    const int tap = it - cc * 9;
    const int kh = (tap * 11) >> 5;       // tap/3 for tap<9
    const int kw = tap - kh * 3;
    const int off = (kh * WP + kw) * 256 + cc * 64 + quad * 8;
    #pragma unroll
    for (int r = 0; r < 2; ++r)
      #pragma unroll
      for (int s = 0; s < 2; ++s)
        dst[r][s] = *(const bf16x8*)(xpad + P[r] + off + s * 32);
  };
  auto compute = [&](int buf, bf16x8 (&af)[2][2]) {
    const char* lb = (const char*)&lB[buf][0];
    #pragma unroll
    for (int s = 0; s < 2; ++s) {
      bf16x8 bfr[4];
      #pragma unroll
      for (int c = 0; c < 4; ++c) bfr[c] = *(const bf16x8*)(lb + boff[c][s]);
      #pragma unroll
      for (int r = 0; r < 2; ++r)
        #pragma unroll
        for (int c = 0; c < 4; ++c)
          acc[r][c] = __builtin_amdgcn_mfma_f32_16x16x32_bf16(af[r][s], bfr[c], acc[r][c], 0, 0, 0);
    }
  };

  stageB(0, 0);
  loadA(0, Ar[0]);
  for (int it = 0; it < 36; it += 2) {
    __syncthreads();                       // lB[0]+Ar[0] for step it ready
    stageB(it + 1, 1);
    loadA(it + 1, Ar[1]);
    compute(0, Ar[0]);
    __syncthreads();                       // lB[1]+Ar[1] for step it+1 ready
    if (it + 2 < 36) {
      stageB(it + 2, 0);
      loadA(it + 2, Ar[0]);
    }
    compute(1, Ar[1]);
  }

  // epilogue: row(M) = wv*32 + r*16 + quad*4 + reg, col(N) = c*16 + l15
  float* obase = out + (size_t)bidx * (COUT * 1024);
  #pragma unroll
  for (int c = 0; c < 4; ++c) {
    const int co = n0 + c * 16 + l15;
    const float bv = bias[co];
    #pragma unroll
    for (int r = 0; r < 2; ++r) {
      const int q = q0 + wv * 32 + r * 16 + quad * 4;
      f32x4 v = acc[r][c];
      v += bv;
      *(f32x4*)(obase + (size_t)co * 1024 + q) = v;
    }
  }
}

extern "C" void kernel_launch(void* const* d_in, const int* in_sizes, int n_in,
                              void* d_out, int out_size, void* d_ws, size_t ws_size,
                              hipStream_t stream) {
  const float* x    = (const float*)d_in[0];
  const float* w    = (const float*)d_in[1];
  const float* bias = (const float*)d_in[2];
  float* out = (float*)d_out;
  uint16_t* xpad = (uint16_t*)d_ws;
  uint16_t* bwq  = xpad + XPAD_ELEMS;          // 256*2304 bf16

  prep_kernel<<<dim3(3376), dim3(256), 0, stream>>>(x, w, xpad, bwq);
  gemm_kernel<<<dim3(512), dim3(256), 0, stream>>>(xpad, bwq, bias, out);
}

// Round 7
// 149.506 us; speedup vs baseline: 1.0602x; 1.0602x over previous
//
#include <hip/hip_runtime.h>
#include <cstdint>

typedef __attribute__((ext_vector_type(8))) __bf16 bf16x8;
typedef __attribute__((ext_vector_type(4))) float f32x4;
typedef __attribute__((ext_vector_type(4))) uint32_t u32x4;

// ---- problem constants ----
#define NB   16
#define CIN  256
#define COUT 256
#define HP   66          // padded H
#define WP   66          // padded W
#define KTOT 2304        // 9*256
#define XPB  (HP*WP*256)            // elems per batch image = 1,115,136
#define XPAD_ELEMS (NB*XPB)

__device__ __forceinline__ uint16_t f2bf(float f) {
  uint32_t u = __builtin_bit_cast(uint32_t, f);
  u = (u + 0x7FFFu + ((u >> 16) & 1u)) >> 16;   // round-to-nearest-even
  return (uint16_t)u;
}

// ---------------- fused prep: xpose (2048 blk) | border (1040 blk) | wprep (288 blk)
__global__ void prep_kernel(const float* __restrict__ x, const float* __restrict__ w,
                            uint16_t* __restrict__ xpad, uint16_t* __restrict__ bw) {
  const int bid = blockIdx.x;
  const int tid = threadIdx.x;
  if (bid < 2048) {
    // transpose+cast: x NCHW fp32 -> xpad[b][h+1][w+1][c] bf16 (interior only)
    const int lane = tid & 63;
    const int wvi = tid >> 6;                 // 0..3
    const int chalf = bid & 1;
    const int h = (bid >> 1) & 63;
    const int b = bid >> 7;
    const int c0 = chalf * 128 + wvi * 32;
    const float* src = x + ((size_t)(b * 256 + c0) * 64 + h) * 64 + lane;
    uint16_t* dst = xpad + ((size_t)(b * HP + h + 1) * WP + lane + 1) * 256 + c0;
    #pragma unroll
    for (int g = 0; g < 4; ++g) {             // 8 channels per 16B store
      u32x4 d;
      #pragma unroll
      for (int k = 0; k < 4; ++k) {
        const float v0 = src[(size_t)(g * 8 + 2 * k + 0) * 4096];
        const float v1 = src[(size_t)(g * 8 + 2 * k + 1) * 4096];
        d[k] = (uint32_t)f2bf(v0) | ((uint32_t)f2bf(v1) << 16);
      }
      *(u32x4*)(dst + g * 8) = d;
    }
  } else if (bid < 3088) {
    // zero the pad border (u64 stores)
    const int idx = (bid - 2048) * 256 + tid;   // 0 .. 266239 exact
    const int b = idx / 16640;
    const int r = idx - b * 16640;
    uint64_t* base = (uint64_t*)(xpad + (size_t)b * XPB);
    int off;
    if (r < 4224) {                    // h=0 full row
      off = r;
    } else if (r < 8448) {             // h=65 full row
      off = 274560 + (r - 4224);
    } else if (r < 12544) {            // w=0 column, h=1..64
      const int i = r - 8448;
      off = (1 + (i >> 6)) * 4224 + (i & 63);
    } else {                           // w=65 column, h=1..64
      const int i = r - 12544;
      off = (1 + (i >> 6)) * 4224 + 4160 + (i & 63);
    }
    base[off] = 0;
  } else {
    // weight reorder: w[co][ci][3][3] fp32 -> bw[co][tap][ci] bf16
    const int gid = (bid - 3088) * 256 + tid;   // 0 .. 73727
    const int co = gid / 288;                   // 288 = 9 taps * 32 ci-groups
    const int r = gid - co * 288;
    const int tap = r >> 5;
    const int ci0 = (r & 31) * 8;
    u32x4 d;
    #pragma unroll
    for (int k = 0; k < 4; ++k) {
      const float v0 = w[((co * 256 + ci0 + 2 * k + 0) * 9) + tap];
      const float v1 = w[((co * 256 + ci0 + 2 * k + 1) * 9) + tap];
      d[k] = (uint32_t)f2bf(v0) | ((uint32_t)f2bf(v1) << 16);
    }
    *(u32x4*)(bw + co * KTOT + tap * 256 + ci0) = d;
  }
}

// ---------------- async 16B global -> LDS --------------------------------------------
__device__ __forceinline__ void gl_lds16(const void* g, void* l) {
  __builtin_amdgcn_global_load_lds(
      (__attribute__((address_space(1))) void*)(uintptr_t)g,
      (__attribute__((address_space(3))) void*)(uint32_t)(uintptr_t)l,
      16, 0, 0);
}

// ---------------- implicit GEMM: BM=128, BN=128, BK=64; 256 threads (4 waves) -------
// wave grid 2x2 (wave tile 64x64). 3-stage LDS pipeline (96 KB) with RAW s_barrier +
// fine-grained s_waitcnt vmcnt(8): stage it+2 stays in flight across the barrier
// (hipBLASLt-style K-loop; __syncthreads' vmcnt(0) drain was the r3/r5 stall).
// K order: ci-chunk OUTER, tap INNER (A slab L2-resident). 256 blocks = 1/CU.
__global__ __launch_bounds__(256, 1) void gemm_kernel(
    const uint16_t* __restrict__ xpad, const uint16_t* __restrict__ bw,
    const float* __restrict__ bias, float* __restrict__ out) {
  __shared__ uint16_t lA[3][128 * 64];   // 16 KB per stage
  __shared__ uint16_t lB[3][128 * 64];   // 16 KB per stage
  const int tid = threadIdx.x;
  const int wv = tid >> 6, lane = tid & 63;
  const int wr = wv >> 1, wc = wv & 1;
  const int quad = lane >> 4, l15 = lane & 15, l7 = lane & 7;

  // XCD swizzle: the 2 n-tiles of one m-tile adjacent on one XCD -> A L2-reuse
  const int xcd = blockIdx.x & 7;
  const int grp = blockIdx.x >> 3;        // 0..31 per XCD
  const int mtile = (xcd << 4) + (grp >> 1);
  const int ntile = grp & 1;
  const int n0 = ntile * 128;
  const int m0 = mtile * 128;
  const int bidx = m0 >> 10;              // batch image
  const int q0 = m0 & 1023;               // permuted pixel offset (multiple of 128)

  // A staging: 4 chunk-slots/thread (1024 chunks of 16B); XOR chunk swizzle
  int a_goff[4];
  #pragma unroll
  for (int t = 0; t < 4; ++t) {
    const int slot = t * 256 + tid;
    const int row = slot >> 3;
    const int kc = (slot & 7) ^ (row & 7);
    const int p = q0 + row;
    const int oh = 2 * ((p >> 4) & 15) + ((p >> 9) & 1);
    const int ow = 2 * (p & 15) + ((p >> 8) & 1);
    a_goff[t] = ((bidx * HP + 2 * oh) * WP + 2 * ow) * 256 + kc * 8;
  }
  // B staging: 4 chunk-slots/thread (1024 chunks)
  int b_goff[4];
  #pragma unroll
  for (int t = 0; t < 4; ++t) {
    const int slot = t * 256 + tid;
    const int n = slot >> 3;
    const int kc = (slot & 7) ^ (n & 7);
    b_goff[t] = (n0 + n) * KTOT + kc * 8;
  }

  // LDS frag byte-offsets (swizzle-matched; 0 conflicts measured r1-r6)
  int aoff[4][2], boff[4][2];
  #pragma unroll
  for (int r = 0; r < 4; ++r)
    #pragma unroll
    for (int s = 0; s < 2; ++s)
      aoff[r][s] = (wr * 64 + r * 16 + l15) * 128 + (((s * 4 + quad) ^ l7) * 16);
  #pragma unroll
  for (int c = 0; c < 4; ++c)
    #pragma unroll
    for (int s = 0; s < 2; ++s)
      boff[c][s] = (wc * 64 + c * 16 + l15) * 128 + (((s * 4 + quad) ^ l7) * 16);

  f32x4 acc[4][4];
  #pragma unroll
  for (int r = 0; r < 4; ++r)
    #pragma unroll
    for (int c = 0; c < 4; ++c)
      acc[r][c] = (f32x4){0.f, 0.f, 0.f, 0.f};

  // K-step decode: it in [0,36); cc = it/9 (ci chunk, OUTER), tap = it%9 (INNER)
  auto stageK = [&](int it, int slot) {
    const int cc = (it * 57) >> 9;        // it/9 for it<36
    const int tap = it - cc * 9;
    const int kh = (tap * 11) >> 5;       // tap/3 for tap<9
    const int kw = tap - kh * 3;
    const uint16_t* aptr = xpad + (kh * WP + kw) * 256 + cc * 64;
    const uint16_t* bptr = bw + tap * 256 + cc * 64;
    char* la = (char*)&lA[slot][0];
    char* lb = (char*)&lB[slot][0];
    #pragma unroll
    for (int t = 0; t < 4; ++t)
      gl_lds16(aptr + a_goff[t], la + (t * 256 + wv * 64) * 16);
    #pragma unroll
    for (int t = 0; t < 4; ++t)
      gl_lds16(bptr + b_goff[t], lb + (t * 256 + wv * 64) * 16);
  };
  auto compute = [&](int slot) {
    const char* la = (const char*)&lA[slot][0];
    const char* lb = (const char*)&lB[slot][0];
    #pragma unroll
    for (int s = 0; s < 2; ++s) {
      bf16x8 af[4], bfr[4];
      #pragma unroll
      for (int r = 0; r < 4; ++r) af[r] = *(const bf16x8*)(la + aoff[r][s]);
      #pragma unroll
      for (int c = 0; c < 4; ++c) bfr[c] = *(const bf16x8*)(lb + boff[c][s]);
      #pragma unroll
      for (int r = 0; r < 4; ++r)
        #pragma unroll
        for (int c = 0; c < 4; ++c)
          acc[r][c] = __builtin_amdgcn_mfma_f32_16x16x32_bf16(af[r], bfr[c], acc[r][c], 0, 0, 0);
    }
  };

  // 3-stage software pipeline with raw barriers + fine-grained vmcnt.
  // Each stage = 8 DMA instrs/wave. In steady state, at iter top: stages it (8)
  // and it+1 (8) outstanding -> vmcnt(8) waits stage it only; stage it+1 stays
  // in flight ACROSS the barrier. Slot (it+2)%3 was consumed at iter it-1; the
  // barrier at iter-it top makes its reuse safe.
  stageK(0, 0);
  stageK(1, 1);
  for (int it = 0; it < 36; ++it) {
    if (it < 35)
      asm volatile("s_waitcnt vmcnt(8) lgkmcnt(0)" ::: "memory");
    else
      asm volatile("s_waitcnt vmcnt(0) lgkmcnt(0)" ::: "memory");
    asm volatile("s_barrier" ::: "memory");
    if (it + 2 < 36) stageK(it + 2, (it + 2) % 3);
    compute(it % 3);
  }

  // epilogue: row(M) = wr*64 + r*16 + quad*4 + reg, col(N) = wc*64 + c*16 + l15
  float* obase = out + (size_t)bidx * (COUT * 1024);
  #pragma unroll
  for (int c = 0; c < 4; ++c) {
    const int co = n0 + wc * 64 + c * 16 + l15;
    const float bv = bias[co];
    #pragma unroll
    for (int r = 0; r < 4; ++r) {
      const int q = q0 + wr * 64 + r * 16 + quad * 4;
      f32x4 v = acc[r][c];
      v += bv;
      *(f32x4*)(obase + (size_t)co * 1024 + q) = v;
    }
  }
}

extern "C" void kernel_launch(void* const* d_in, const int* in_sizes, int n_in,
                              void* d_out, int out_size, void* d_ws, size_t ws_size,
                              hipStream_t stream) {
  const float* x    = (const float*)d_in[0];
  const float* w    = (const float*)d_in[1];
  const float* bias = (const float*)d_in[2];
  float* out = (float*)d_out;
  uint16_t* xpad = (uint16_t*)d_ws;
  uint16_t* bwq  = xpad + XPAD_ELEMS;          // 256*2304 bf16

  prep_kernel<<<dim3(3376), dim3(256), 0, stream>>>(x, w, xpad, bwq);
  gemm_kernel<<<dim3(256), dim3(256), 0, stream>>>(xpad, bwq, bias, out);
}

// Round 8
// 141.693 us; speedup vs baseline: 1.1186x; 1.0551x over previous
//
#include <hip/hip_runtime.h>
#include <cstdint>

typedef __attribute__((ext_vector_type(8))) __bf16 bf16x8;
typedef __attribute__((ext_vector_type(4))) float f32x4;
typedef __attribute__((ext_vector_type(4))) uint32_t u32x4;

// ---- problem constants ----
#define NB   16
#define CIN  256
#define COUT 256
#define HP   66          // padded H
#define WP   66          // padded W
#define KTOT 2304        // 9*256
#define XPB  (HP*WP*256)            // elems per batch image = 1,115,136
#define XPAD_ELEMS (NB*XPB)

__device__ __forceinline__ uint16_t f2bf(float f) {
  uint32_t u = __builtin_bit_cast(uint32_t, f);
  u = (u + 0x7FFFu + ((u >> 16) & 1u)) >> 16;   // round-to-nearest-even
  return (uint16_t)u;
}

// ---------------- fused prep: xpose (2048 blk) | border (1040 blk) | wprep (288 blk)
__global__ void prep_kernel(const float* __restrict__ x, const float* __restrict__ w,
                            uint16_t* __restrict__ xpad, uint16_t* __restrict__ bw) {
  const int bid = blockIdx.x;
  const int tid = threadIdx.x;
  if (bid < 2048) {
    // transpose+cast: x NCHW fp32 -> xpad[b][h+1][w+1][c] bf16 (interior only)
    const int lane = tid & 63;
    const int wvi = tid >> 6;                 // 0..3
    const int chalf = bid & 1;
    const int h = (bid >> 1) & 63;
    const int b = bid >> 7;
    const int c0 = chalf * 128 + wvi * 32;
    const float* src = x + ((size_t)(b * 256 + c0) * 64 + h) * 64 + lane;
    uint16_t* dst = xpad + ((size_t)(b * HP + h + 1) * WP + lane + 1) * 256 + c0;
    #pragma unroll
    for (int g = 0; g < 4; ++g) {             // 8 channels per 16B store
      u32x4 d;
      #pragma unroll
      for (int k = 0; k < 4; ++k) {
        const float v0 = src[(size_t)(g * 8 + 2 * k + 0) * 4096];
        const float v1 = src[(size_t)(g * 8 + 2 * k + 1) * 4096];
        d[k] = (uint32_t)f2bf(v0) | ((uint32_t)f2bf(v1) << 16);
      }
      *(u32x4*)(dst + g * 8) = d;
    }
  } else if (bid < 3088) {
    // zero the pad border (u64 stores)
    const int idx = (bid - 2048) * 256 + tid;   // 0 .. 266239 exact
    const int b = idx / 16640;
    const int r = idx - b * 16640;
    uint64_t* base = (uint64_t*)(xpad + (size_t)b * XPB);
    int off;
    if (r < 4224) {                    // h=0 full row
      off = r;
    } else if (r < 8448) {             // h=65 full row
      off = 274560 + (r - 4224);
    } else if (r < 12544) {            // w=0 column, h=1..64
      const int i = r - 8448;
      off = (1 + (i >> 6)) * 4224 + (i & 63);
    } else {                           // w=65 column, h=1..64
      const int i = r - 12544;
      off = (1 + (i >> 6)) * 4224 + 4160 + (i & 63);
    }
    base[off] = 0;
  } else {
    // weight reorder: w[co][ci][3][3] fp32 -> bw[co][tap][ci] bf16
    const int gid = (bid - 3088) * 256 + tid;   // 0 .. 73727
    const int co = gid / 288;                   // 288 = 9 taps * 32 ci-groups
    const int r = gid - co * 288;
    const int tap = r >> 5;
    const int ci0 = (r & 31) * 8;
    u32x4 d;
    #pragma unroll
    for (int k = 0; k < 4; ++k) {
      const float v0 = w[((co * 256 + ci0 + 2 * k + 0) * 9) + tap];
      const float v1 = w[((co * 256 + ci0 + 2 * k + 1) * 9) + tap];
      d[k] = (uint32_t)f2bf(v0) | ((uint32_t)f2bf(v1) << 16);
    }
    *(u32x4*)(bw + co * KTOT + tap * 256 + ci0) = d;
  }
}

// ---------------- async 16B global -> LDS --------------------------------------------
__device__ __forceinline__ void gl_lds16(const void* g, void* l) {
  __builtin_amdgcn_global_load_lds(
      (__attribute__((address_space(1))) void*)(uintptr_t)g,
      (__attribute__((address_space(3))) void*)(uint32_t)(uintptr_t)l,
      16, 0, 0);
}

// ---------------- implicit GEMM: BM=128, BN=64, BK=64; 256 threads (4 waves) --------
// r3's occupancy shape (512 blocks = 2 blk/CU = 8 waves/CU) + hipBLASLt-style K-loop:
// 3-stage LDS pipeline (72 KB/block, 2 blocks/CU = 144 <= 160 KB) with RAW s_barrier
// + s_waitcnt vmcnt(6) — next stage's 6 DMAs stay in flight across the barrier,
// killing the vmcnt(0) drain that cost r3 ~20%. ci-chunk OUTER K order keeps the
// A slab L2-resident (r6: FETCH 26->21.5 MB).
__global__ __launch_bounds__(256, 2) void gemm_kernel(
    const uint16_t* __restrict__ xpad, const uint16_t* __restrict__ bw,
    const float* __restrict__ bias, float* __restrict__ out) {
  __shared__ uint16_t lA[3][128 * 64];   // 16 KB per stage
  __shared__ uint16_t lB[3][64 * 64];    //  8 KB per stage
  const int tid = threadIdx.x;
  const int wv = tid >> 6, lane = tid & 63;
  const int quad = lane >> 4, l15 = lane & 15, l7 = lane & 7;

  // XCD swizzle: 4 n-tiles of one m-tile co-resident on one XCD -> A L2-reuse
  const int xcd = blockIdx.x & 7;
  const int grp = blockIdx.x >> 3;        // 0..63 per XCD
  const int mtile = (xcd << 4) + (grp >> 2);
  const int ntile = grp & 3;
  const int n0 = ntile * 64;
  const int m0 = mtile * 128;
  const int bidx = m0 >> 10;              // batch image
  const int q0 = m0 & 1023;               // permuted pixel offset (multiple of 128)

  // A staging: 4 chunk-slots/thread (1024 chunks of 16B); XOR chunk swizzle
  int a_goff[4];
  #pragma unroll
  for (int t = 0; t < 4; ++t) {
    const int slot = t * 256 + tid;
    const int row = slot >> 3;
    const int kc = (slot & 7) ^ (row & 7);
    const int p = q0 + row;
    const int oh = 2 * ((p >> 4) & 15) + ((p >> 9) & 1);
    const int ow = 2 * (p & 15) + ((p >> 8) & 1);
    a_goff[t] = ((bidx * HP + 2 * oh) * WP + 2 * ow) * 256 + kc * 8;
  }
  // B staging: 2 chunk-slots/thread (512 chunks)
  int b_goff[2];
  #pragma unroll
  for (int t = 0; t < 2; ++t) {
    const int slot = t * 256 + tid;
    const int n = slot >> 3;
    const int kc = (slot & 7) ^ (n & 7);
    b_goff[t] = (n0 + n) * KTOT + kc * 8;
  }

  // LDS frag byte-offsets (swizzle-matched; 0 conflicts measured r1-r7)
  int aoff[2][2], boff[4][2];
  #pragma unroll
  for (int r = 0; r < 2; ++r)
    #pragma unroll
    for (int s = 0; s < 2; ++s)
      aoff[r][s] = (wv * 32 + r * 16 + l15) * 128 + (((s * 4 + quad) ^ l7) * 16);
  #pragma unroll
  for (int c = 0; c < 4; ++c)
    #pragma unroll
    for (int s = 0; s < 2; ++s)
      boff[c][s] = (c * 16 + l15) * 128 + (((s * 4 + quad) ^ l7) * 16);

  f32x4 acc[2][4];
  #pragma unroll
  for (int r = 0; r < 2; ++r)
    #pragma unroll
    for (int c = 0; c < 4; ++c)
      acc[r][c] = (f32x4){0.f, 0.f, 0.f, 0.f};

  // K-step decode: it in [0,36); cc = it/9 (ci chunk, OUTER), tap = it%9 (INNER)
  auto stageK = [&](int it, int slot) {
    const int cc = (it * 57) >> 9;        // it/9 for it<36
    const int tap = it - cc * 9;
    const int kh = (tap * 11) >> 5;       // tap/3 for tap<9
    const int kw = tap - kh * 3;
    const uint16_t* aptr = xpad + (kh * WP + kw) * 256 + cc * 64;
    const uint16_t* bptr = bw + tap * 256 + cc * 64;
    char* la = (char*)&lA[slot][0];
    char* lb = (char*)&lB[slot][0];
    #pragma unroll
    for (int t = 0; t < 4; ++t)
      gl_lds16(aptr + a_goff[t], la + (t * 256 + wv * 64) * 16);
    #pragma unroll
    for (int t = 0; t < 2; ++t)
      gl_lds16(bptr + b_goff[t], lb + (t * 256 + wv * 64) * 16);
  };
  auto compute = [&](int slot) {
    const char* la = (const char*)&lA[slot][0];
    const char* lb = (const char*)&lB[slot][0];
    #pragma unroll
    for (int s = 0; s < 2; ++s) {
      bf16x8 af[2], bfr[4];
      #pragma unroll
      for (int r = 0; r < 2; ++r) af[r] = *(const bf16x8*)(la + aoff[r][s]);
      #pragma unroll
      for (int c = 0; c < 4; ++c) bfr[c] = *(const bf16x8*)(lb + boff[c][s]);
      #pragma unroll
      for (int r = 0; r < 2; ++r)
        #pragma unroll
        for (int c = 0; c < 4; ++c)
          acc[r][c] = __builtin_amdgcn_mfma_f32_16x16x32_bf16(af[r], bfr[c], acc[r][c], 0, 0, 0);
    }
  };

  // 3-stage pipeline, raw barriers, fine-grained vmcnt. Stage = 6 DMA instrs/wave.
  // Steady state at iter top: stages it (6) + it+1 (6) outstanding; vmcnt(6) waits
  // only stage it — stage it+1 crosses the barrier in flight. Slot (it+2)%3 was
  // consumed at iter it-1, so the barrier at iter it makes its reuse safe.
  stageK(0, 0);
  stageK(1, 1);
  for (int it = 0; it < 36; ++it) {
    if (it < 35)
      asm volatile("s_waitcnt vmcnt(6) lgkmcnt(0)" ::: "memory");
    else
      asm volatile("s_waitcnt vmcnt(0) lgkmcnt(0)" ::: "memory");
    asm volatile("s_barrier" ::: "memory");
    if (it + 2 < 36) stageK(it + 2, (it + 2) % 3);
    compute(it % 3);
  }

  // epilogue: row(M) = wv*32 + r*16 + quad*4 + reg, col(N) = c*16 + l15
  float* obase = out + (size_t)bidx * (COUT * 1024);
  #pragma unroll
  for (int c = 0; c < 4; ++c) {
    const int co = n0 + c * 16 + l15;
    const float bv = bias[co];
    #pragma unroll
    for (int r = 0; r < 2; ++r) {
      const int q = q0 + wv * 32 + r * 16 + quad * 4;
      f32x4 v = acc[r][c];
      v += bv;
      *(f32x4*)(obase + (size_t)co * 1024 + q) = v;
    }
  }
}

extern "C" void kernel_launch(void* const* d_in, const int* in_sizes, int n_in,
                              void* d_out, int out_size, void* d_ws, size_t ws_size,
                              hipStream_t stream) {
  const float* x    = (const float*)d_in[0];
  const float* w    = (const float*)d_in[1];
  const float* bias = (const float*)d_in[2];
  float* out = (float*)d_out;
  uint16_t* xpad = (uint16_t*)d_ws;
  uint16_t* bwq  = xpad + XPAD_ELEMS;          // 256*2304 bf16

  prep_kernel<<<dim3(3376), dim3(256), 0, stream>>>(x, w, xpad, bwq);
  gemm_kernel<<<dim3(512), dim3(256), 0, stream>>>(xpad, bwq, bias, out);
}